// Round 11
// baseline (74.027 us; speedup 1.0000x reference)
//
#include <hip/hip_runtime.h>
#include <hip/hip_bf16.h>

#define M_ROWS 8192
#define K_DIM 128
#define NCLS 60
#define NPAN 32            // 256-row/col panels; denomP has NPAN slots
#define NSLAB 128          // kprep partial class tables

// x = q_i . q_j where q = bf16(fhat * SCL), SCL^2 = 5*log2(e)  ->  sim = x*ln2, exp(sim) = 2^x
constexpr float SCL = 2.68579007f;     // sqrt(5 * 1.4426950408889634)
constexpr float LN2 = 0.69314718056f;

using f32x4 = __attribute__((ext_vector_type(4))) float;
using s16x8 = __attribute__((ext_vector_type(8))) short;

__device__ inline float bf2f(ushort u) {
    union { unsigned int i; float f; } v; v.i = ((unsigned int)u) << 16; return v.f;
}
__device__ inline float fexp2(float x) {
#if __has_builtin(__builtin_amdgcn_exp2f)
    return __builtin_amdgcn_exp2f(x);
#else
    return exp2f(x);
#endif
}

// packed fragment-major layout: ushort index = c16*2048 + kk*512 + lane*8
//   (c16 = row/16 block, kk = k/32, lane = g*16+lrow; chunk = row c16*16+lrow,
//    k = kk*32 + g*8 .. +8 — exactly one MFMA fragment per 64-lane load)

// ---------------- fused: normalize -> fnr + fnp, class partials -> slab ----------------
// 128 blocks x 64 rows.
__global__ __launch_bounds__(256) void kprep(const float* __restrict__ feat,
                                             const int* __restrict__ labels,
                                             ushort* __restrict__ fnr,
                                             ushort* __restrict__ fnp,
                                             float* __restrict__ slabS,
                                             float* __restrict__ slabC) {
    __shared__ ushort ln[64][136];       // padded stride vs bank conflicts
    __shared__ float Sl[NCLS * K_DIM];   // 30 KB
    __shared__ float Cl[NCLS];
    __shared__ int lab[64];
    const int tid = threadIdx.x, wv = tid >> 6, lane = tid & 63;
    const int rbase = blockIdx.x * 64;
    for (int i = tid; i < NCLS * K_DIM; i += 256) Sl[i] = 0.f;
    if (tid < NCLS) Cl[tid] = 0.f;
    if (tid < 64) lab[tid] = labels[rbase + tid];

    // normalize: each wave owns 16 rows
    for (int it = 0; it < 16; ++it) {
        const int r = wv * 16 + it;
        const int grow = rbase + r;
        const float2 v = *(const float2*)&feat[(size_t)grow * K_DIM + lane * 2];
        float ss = v.x * v.x + v.y * v.y;
#pragma unroll
        for (int m = 1; m < 64; m <<= 1) ss += __shfl_xor(ss, m, 64);
        const float rs = rsqrtf(ss) * SCL;
        __hip_bfloat16 ha = __float2bfloat16(v.x * rs);
        __hip_bfloat16 hb = __float2bfloat16(v.y * rs);
        ushort2 o;
        o.x = *reinterpret_cast<const ushort*>(&ha);
        o.y = *reinterpret_cast<const ushort*>(&hb);
        *(ushort2*)&fnr[(size_t)grow * K_DIM + lane * 2] = o;
        *(ushort2*)&ln[r][lane * 2] = o;
    }
    __syncthreads();

    // packed fnp: 4 row-groups of 16
#pragma unroll
    for (int it = 0; it < 4; ++it) {
        const int b = blockIdx.x * 4 + it;
        const s16x8 vv = *(const s16x8*)&ln[it * 16 + (tid & 15)][(tid >> 4) * 8];
        *(s16x8*)&fnp[(size_t)b * 2048 + tid * 8] = vv;
    }

    // class partials from LDS
    const int rsub = tid >> 4;
    const int kc = tid & 15;
#pragma unroll
    for (int it = 0; it < 4; ++it) {
        const int r = it * 16 + rsub;
        const int lb = lab[r];
        if (kc == 0) atomicAdd(&Cl[lb], 1.f);
        const s16x8 q = *(const s16x8*)&ln[r][kc * 8];
        float* dst = &Sl[lb * K_DIM + kc * 8];
#pragma unroll
        for (int j = 0; j < 8; ++j) atomicAdd(&dst[j], bf2f((ushort)q[j]));
    }
    __syncthreads();
    float* oS = slabS + (size_t)blockIdx.x * (NCLS * K_DIM);
    for (int i = tid; i < NCLS * K_DIM; i += 256) oS[i] = Sl[i];
    if (tid < NCLS) slabC[blockIdx.x * 64 + tid] = Cl[tid];
}

// ---------------- reduce slabs -> S, cntC; zero denomP and out ----------------
// 32 blocks x 256 = 8192 threads.
__global__ __launch_bounds__(256) void kreduce(const float* __restrict__ slabS,
                                               const float* __restrict__ slabC,
                                               float* __restrict__ S,
                                               float* __restrict__ cntC,
                                               float* __restrict__ denomP,
                                               float* __restrict__ out) {
    const int i = blockIdx.x * 256 + threadIdx.x;
#pragma unroll
    for (int z = 0; z < NPAN; ++z) denomP[(size_t)z * M_ROWS + i] = 0.f;
    if (i == 0) out[0] = 0.f;
    if (i < NCLS * K_DIM) {
        float s = 0.f;
#pragma unroll 8
        for (int b = 0; b < NSLAB; ++b) s += slabS[(size_t)b * (NCLS * K_DIM) + i];
        S[i] = s;
    } else if (i < NCLS * K_DIM + NCLS) {
        const int c = i - NCLS * K_DIM;
        float s = 0.f;
#pragma unroll 8
        for (int b = 0; b < NSLAB; ++b) s += slabC[b * 64 + c];
        cntC[c] = s;
    }
}

// ---------------- main: symmetric upper-tri 256x256 panel blocks ----------------
// Block (I,J), I<=J (528 blocks). 4 waves x 64 rows of panel I; cols = panel J (4 tiles).
// Row partials -> plain store denomP[J][rows of I]; col partials (I<J) ->
// atomicAdd denomP[I][cols of J] (4-way contention, block-local).
__global__ __launch_bounds__(256) void kmain(const ushort* __restrict__ fnp,
                                             float* __restrict__ denomP) {
    const int tid = threadIdx.x;
    const int lane = tid & 63;
    const int lrow = lane & 15;
    const int g = lane >> 4;
    const int wv = tid >> 6;

    // decode blockIdx.x -> (I, J), I <= J < 32; off(I) = 32I - I(I-1)/2
    const int bid = blockIdx.x;
    int I = (int)((65.0f - sqrtf(65.0f * 65.0f - 8.0f * (float)bid)) * 0.5f);
    while ((I + 1) * 32 - ((I + 1) * I) / 2 <= bid) ++I;
    while (I * 32 - (I * (I - 1)) / 2 > bid) --I;
    const int J = I + (bid - (I * 32 - (I * (I - 1)) / 2));
    const bool offd = (J != I);
    const int rbase = I * 256 + wv * 64;

    // persistent A fragments: rows rbase..+63, K=128 (packed, lane-linear)
    s16x8 af[4][4];
#pragma unroll
    for (int m = 0; m < 4; ++m)
#pragma unroll
        for (int kk = 0; kk < 4; ++kk)
            af[m][kk] = *(const s16x8*)&fnp[(size_t)((rbase >> 4) + m) * 2048 + kk * 512 + lane * 8];

    float pd[4][4] = {};  // row partials across all 4 tiles

#pragma unroll
    for (int t = 0; t < 4; ++t) {   // 4 tiles of 64 cols = panel J
        const int c16b = J * 16 + t * 4;
        f32x4 acc[4][4] = {};
#pragma unroll
        for (int kk = 0; kk < 4; ++kk) {
            s16x8 bfr[4];
#pragma unroll
            for (int n = 0; n < 4; ++n)
                bfr[n] = *(const s16x8*)&fnp[(size_t)(c16b + n) * 2048 + kk * 512 + lane * 8];
#pragma unroll
            for (int m = 0; m < 4; ++m)
#pragma unroll
                for (int n = 0; n < 4; ++n)
                    acc[m][n] = __builtin_amdgcn_mfma_f32_16x16x32_bf16(af[m][kk], bfr[n], acc[m][n], 0, 0, 0);
        }
        float pcn[4] = {0.f, 0.f, 0.f, 0.f};
#pragma unroll
        for (int m = 0; m < 4; ++m)
#pragma unroll
            for (int n = 0; n < 4; ++n)
#pragma unroll
                for (int r = 0; r < 4; ++r) {
                    const float e = fexp2(acc[m][n][r]);
                    pd[m][r] += e;
                    pcn[n] += e;
                }
        if (offd) {
#pragma unroll
            for (int n = 0; n < 4; ++n) {
                float v = pcn[n];
                v += __shfl_xor(v, 16);
                v += __shfl_xor(v, 32);
                if (lane < 16)
                    atomicAdd(&denomP[(size_t)I * M_ROWS + J * 256 + t * 64 + n * 16 + lrow], v);
            }
        }
    }

    // row partials -> slot J, plain store (wave owns its rows; slot exclusivity by I<=J)
#pragma unroll
    for (int m = 0; m < 4; ++m)
#pragma unroll
        for (int r = 0; r < 4; ++r) {
            float v = pd[m][r];
#pragma unroll
            for (int msk = 1; msk < 16; msk <<= 1) v += __shfl_xor(v, msk, 16);
            if (lrow == 0)
                denomP[(size_t)J * M_ROWS + rbase + m * 16 + g * 4 + r] = v;
        }
}

// ---------------- finalize: per-row loss, mean ----------------
__global__ __launch_bounds__(1024) void kfin(const ushort* __restrict__ fn,
                                             const int* __restrict__ labels,
                                             const float* __restrict__ denomP,
                                             const float* __restrict__ S,
                                             const float* __restrict__ cntC,
                                             float* __restrict__ out) {
    const int tid = threadIdx.x;
    const int wv = tid >> 6, lane = tid & 63;
    const int row = blockIdx.x * 16 + wv;
    const ushort2 qv = *(const ushort2*)&fn[(size_t)row * K_DIM + lane * 2];
    const float f0 = bf2f(qv.x), f1 = bf2f(qv.y);
    const int c = labels[row];
    const float2 sv = *(const float2*)&S[c * K_DIM + lane * 2];
    float dot = f0 * sv.x + f1 * sv.y;   // q_i . S_c  (includes self)
    float sii = f0 * f0 + f1 * f1;       // q_i . q_i
#pragma unroll
    for (int msk = 1; msk < 64; msk <<= 1) {
        dot += __shfl_xor(dot, msk, 64);
        sii += __shfl_xor(sii, msk, 64);
    }
    // gather the 32 panel-slot partials for this row
    float dsum = (lane < NPAN) ? denomP[(size_t)lane * M_ROWS + row] : 0.f;
#pragma unroll
    for (int msk = 1; msk < 32; msk <<= 1) dsum += __shfl_xor(dsum, msk, 32);

    __shared__ float ls[16];
    if (lane == 0) {
        const float cf = cntC[c];                                   // count incl. self
        const float d = fmaxf(dsum - fexp2(sii), 1e-5f);            // exclude diagonal
        const float p = (dot - sii) * LN2;                          // matched sims, excl diag
        ls[wv] = ((cf - 1.f) * __logf(d) - p) / cf;
    }
    __syncthreads();
    if (tid == 0) {
        float s = 0.f;
#pragma unroll
        for (int i = 0; i < 16; ++i) s += ls[i];
        atomicAdd(out, s * (1.0f / M_ROWS));
    }
}

extern "C" void kernel_launch(void* const* d_in, const int* in_sizes, int n_in,
                              void* d_out, int out_size, void* d_ws, size_t ws_size,
                              hipStream_t stream) {
    (void)in_sizes; (void)n_in; (void)out_size; (void)ws_size;
    const float* feat = (const float*)d_in[0];
    const int* labels = (const int*)d_in[2];   // d_in[1] (ious) unused: coef == 1
    float* out = (float*)d_out;
    char* ws = (char*)d_ws;
    ushort* fnr = (ushort*)ws;                                  // 2 MB row-major bf16
    ushort* fnp = fnr + (size_t)M_ROWS * K_DIM;                 // 2 MB packed fragment-major
    float* denomP = (float*)(fnp + (size_t)M_ROWS * K_DIM);     // 32 x 8192 x 4B = 1 MB
    float* S = denomP + (size_t)NPAN * M_ROWS;                  // 30 KB
    float* cntC = S + NCLS * K_DIM;                             // 256 B
    float* slabS = cntC + 64;                                   // 128 x 30 KB
    float* slabC = slabS + (size_t)NSLAB * NCLS * K_DIM;        // 128 x 256 B

    kprep<<<NSLAB, 256, 0, stream>>>(feat, labels, fnr, fnp, slabS, slabC);
    kreduce<<<NPAN, 256, 0, stream>>>(slabS, slabC, S, cntC, denomP, out);
    kmain<<<528, 256, 0, stream>>>(fnp, denomP);
    kfin<<<M_ROWS / 16, 1024, 0, stream>>>(fnr, labels, denomP, S, cntC, out);
}

// Round 12
// 72.325 us; speedup vs baseline: 1.0235x; 1.0235x over previous
//
#include <hip/hip_runtime.h>
#include <hip/hip_bf16.h>

#define M_ROWS 8192
#define K_DIM 128
#define NCLS 60
#define NPAN 32            // 256-row/col panels; denomP has NPAN slots
#define NSLAB 128          // class partial tables

// x = q_i . q_j where q = bf16(fhat * SCL), SCL^2 = 5*log2(e)  ->  sim = x*ln2, exp(sim) = 2^x
constexpr float SCL = 2.68579007f;     // sqrt(5 * 1.4426950408889634)
constexpr float LN2 = 0.69314718056f;

using f32x4 = __attribute__((ext_vector_type(4))) float;
using s16x8 = __attribute__((ext_vector_type(8))) short;

__device__ inline float bf2f(ushort u) {
    union { unsigned int i; float f; } v; v.i = ((unsigned int)u) << 16; return v.f;
}
__device__ inline float fexp2(float x) {
#if __has_builtin(__builtin_amdgcn_exp2f)
    return __builtin_amdgcn_exp2f(x);
#else
    return exp2f(x);
#endif
}

// packed fragment-major layout: ushort index = c16*2048 + kk*512 + lane*8
//   (c16 = row/16 block, kk = k/32, lane = g*16+lrow; one MFMA fragment per 64-lane load)

// ---------------- normalize + emit row-major fnr AND packed fnp (512 blocks) ----------------
__global__ __launch_bounds__(256) void knorm(const float* __restrict__ feat,
                                             ushort* __restrict__ fnr,
                                             ushort* __restrict__ fnp) {
    __shared__ ushort ln[16][128];
    const int wv = threadIdx.x >> 6, lane = threadIdx.x & 63;
    int row = wv * 4;   // local row within this block's 16
#pragma unroll
    for (int it = 0; it < 4; ++it, ++row) {
        const int grow = blockIdx.x * 16 + row;
        const float2 v = *(const float2*)&feat[(size_t)grow * K_DIM + lane * 2];
        float ss = v.x * v.x + v.y * v.y;
#pragma unroll
        for (int m = 1; m < 64; m <<= 1) ss += __shfl_xor(ss, m, 64);
        const float rs = rsqrtf(ss) * SCL;
        __hip_bfloat16 ha = __float2bfloat16(v.x * rs);
        __hip_bfloat16 hb = __float2bfloat16(v.y * rs);
        ushort2 o;
        o.x = *reinterpret_cast<const ushort*>(&ha);
        o.y = *reinterpret_cast<const ushort*>(&hb);
        *(ushort2*)&fnr[(size_t)grow * K_DIM + lane * 2] = o;
        *(ushort2*)&ln[row][lane * 2] = o;
    }
    __syncthreads();
    // packed write: thread tid emits chunk (c16-block = blockIdx, row = tid&15, k-chunk = tid>>4)
    const int tid = threadIdx.x;
    const s16x8 vv = *(const s16x8*)&ln[tid & 15][(tid >> 4) * 8];
    *(s16x8*)&fnp[(size_t)blockIdx.x * 2048 + tid * 8] = vv;
}

// ---------------- class partials: 128 blocks x 64 rows, LDS table -> slab ----------------
__global__ __launch_bounds__(256) void kclassp(const ushort* __restrict__ fn,
                                               const int* __restrict__ labels,
                                               float* __restrict__ slabS,
                                               float* __restrict__ slabC) {
    __shared__ float Sl[NCLS * K_DIM];   // 30 KB
    __shared__ float Cl[NCLS];
    __shared__ int lab[64];
    const int tid = threadIdx.x;
    const int rbase = blockIdx.x * 64;
    for (int i = tid; i < NCLS * K_DIM; i += 256) Sl[i] = 0.f;
    if (tid < NCLS) Cl[tid] = 0.f;
    if (tid < 64) lab[tid] = labels[rbase + tid];
    __syncthreads();

    const int rsub = tid >> 4;           // 16 rows concurrent
    const int kc = tid & 15;             // 16 lanes x 8 bf16 = 128 k
#pragma unroll
    for (int it = 0; it < 4; ++it) {
        const int r = it * 16 + rsub;
        const int lb = lab[r];
        if (kc == 0) atomicAdd(&Cl[lb], 1.f);
        const s16x8 q = *(const s16x8*)&fn[(size_t)(rbase + r) * K_DIM + kc * 8];
        float* dst = &Sl[lb * K_DIM + kc * 8];
#pragma unroll
        for (int j = 0; j < 8; ++j) atomicAdd(&dst[j], bf2f((ushort)q[j]));
    }
    __syncthreads();
    float* oS = slabS + (size_t)blockIdx.x * (NCLS * K_DIM);
    for (int i = tid; i < NCLS * K_DIM; i += 256) oS[i] = Sl[i];
    if (tid < NCLS) slabC[blockIdx.x * 64 + tid] = Cl[tid];
}

// ---------------- reduce slabs -> S, cntC; zero out ----------------
__global__ __launch_bounds__(256) void kreduce(const float* __restrict__ slabS,
                                               const float* __restrict__ slabC,
                                               float* __restrict__ S,
                                               float* __restrict__ cntC,
                                               float* __restrict__ out) {
    const int i = blockIdx.x * 256 + threadIdx.x;
    if (i == 0) out[0] = 0.f;
    if (i < NCLS * K_DIM) {
        float s = 0.f;
#pragma unroll 8
        for (int b = 0; b < NSLAB; ++b) s += slabS[(size_t)b * (NCLS * K_DIM) + i];
        S[i] = s;
    } else if (i < NCLS * K_DIM + NCLS) {
        const int c = i - NCLS * K_DIM;
        float s = 0.f;
#pragma unroll 8
        for (int b = 0; b < NSLAB; ++b) s += slabC[b * 64 + c];
        cntC[c] = s;
    }
}

// ---------------- main: symmetric upper-tri 256x256 panel blocks, atomic-free ----------------
// Block (I,J), I<=J (528). 4 waves x 64 rows of panel I; cols = panel J (4 tiles of 64).
// Row partials -> plain store denomP[J][rows of I] (wave-exclusive).
// Col partials (I<J) -> 4KB LDS cross-wave reduce, plain store denomP[I][cols of J].
// Slot coverage for row in panel P: s>=P from block (P,s) rows; s<P from block (s,P) cols.
__global__ __launch_bounds__(256) void kmain(const ushort* __restrict__ fnp,
                                             float* __restrict__ denomP) {
    __shared__ float colbuf[4][256];   // 4 KB
    const int tid = threadIdx.x;
    const int lane = tid & 63;
    const int lrow = lane & 15;
    const int g = lane >> 4;
    const int wv = tid >> 6;

    // decode blockIdx.x -> (I, J), I <= J < 32; off(I) = 32I - I(I-1)/2
    const int bid = blockIdx.x;
    int I = (int)((65.0f - sqrtf(65.0f * 65.0f - 8.0f * (float)bid)) * 0.5f);
    while ((I + 1) * 32 - ((I + 1) * I) / 2 <= bid) ++I;
    while (I * 32 - (I * (I - 1)) / 2 > bid) --I;
    const int J = I + (bid - (I * 32 - (I * (I - 1)) / 2));
    const bool offd = (J != I);
    const int rbase = I * 256 + wv * 64;

    // persistent A fragments: rows rbase..+63, K=128 (packed, lane-linear)
    s16x8 af[4][4];
#pragma unroll
    for (int m = 0; m < 4; ++m)
#pragma unroll
        for (int kk = 0; kk < 4; ++kk)
            af[m][kk] = *(const s16x8*)&fnp[(size_t)((rbase >> 4) + m) * 2048 + kk * 512 + lane * 8];

    float pd[4][4] = {};  // row partials across all 4 tiles

#pragma unroll
    for (int t = 0; t < 4; ++t) {   // 4 tiles of 64 cols = panel J
        const int c16b = J * 16 + t * 4;
        f32x4 acc[4][4] = {};
#pragma unroll
        for (int kk = 0; kk < 4; ++kk) {
            s16x8 bfr[4];
#pragma unroll
            for (int n = 0; n < 4; ++n)
                bfr[n] = *(const s16x8*)&fnp[(size_t)(c16b + n) * 2048 + kk * 512 + lane * 8];
#pragma unroll
            for (int m = 0; m < 4; ++m)
#pragma unroll
                for (int n = 0; n < 4; ++n)
                    acc[m][n] = __builtin_amdgcn_mfma_f32_16x16x32_bf16(af[m][kk], bfr[n], acc[m][n], 0, 0, 0);
        }
        float pcn[4] = {0.f, 0.f, 0.f, 0.f};
#pragma unroll
        for (int m = 0; m < 4; ++m)
#pragma unroll
            for (int n = 0; n < 4; ++n)
#pragma unroll
                for (int r = 0; r < 4; ++r) {
                    const float e = fexp2(acc[m][n][r]);
                    pd[m][r] += e;
                    pcn[n] += e;
                }
        if (offd) {
#pragma unroll
            for (int n = 0; n < 4; ++n) {
                float v = pcn[n];
                v += __shfl_xor(v, 16);
                v += __shfl_xor(v, 32);
                if (lane < 16) colbuf[wv][t * 64 + n * 16 + lrow] = v;
            }
        }
    }

    // row partials -> slot J, plain store (wave owns its rows)
#pragma unroll
    for (int m = 0; m < 4; ++m)
#pragma unroll
        for (int r = 0; r < 4; ++r) {
            float v = pd[m][r];
#pragma unroll
            for (int msk = 1; msk < 16; msk <<= 1) v += __shfl_xor(v, msk, 16);
            if (lrow == 0)
                denomP[(size_t)J * M_ROWS + rbase + m * 16 + g * 4 + r] = v;
        }

    // col partials: cross-wave LDS reduce -> slot I, plain store (block-uniform branch)
    if (offd) {
        __syncthreads();
        const float cv = colbuf[0][tid] + colbuf[1][tid] + colbuf[2][tid] + colbuf[3][tid];
        denomP[(size_t)I * M_ROWS + J * 256 + tid] = cv;
    }
}

// ---------------- finalize: per-row loss, mean ----------------
__global__ __launch_bounds__(1024) void kfin(const ushort* __restrict__ fn,
                                             const int* __restrict__ labels,
                                             const float* __restrict__ denomP,
                                             const float* __restrict__ S,
                                             const float* __restrict__ cntC,
                                             float* __restrict__ out) {
    const int tid = threadIdx.x;
    const int wv = tid >> 6, lane = tid & 63;
    const int row = blockIdx.x * 16 + wv;
    const ushort2 qv = *(const ushort2*)&fn[(size_t)row * K_DIM + lane * 2];
    const float f0 = bf2f(qv.x), f1 = bf2f(qv.y);
    const int c = labels[row];
    const float2 sv = *(const float2*)&S[c * K_DIM + lane * 2];
    float dot = f0 * sv.x + f1 * sv.y;   // q_i . S_c  (includes self)
    float sii = f0 * f0 + f1 * f1;       // q_i . q_i
#pragma unroll
    for (int msk = 1; msk < 64; msk <<= 1) {
        dot += __shfl_xor(dot, msk, 64);
        sii += __shfl_xor(sii, msk, 64);
    }
    // gather the 32 panel-slot partials for this row
    float dsum = (lane < NPAN) ? denomP[(size_t)lane * M_ROWS + row] : 0.f;
#pragma unroll
    for (int msk = 1; msk < 32; msk <<= 1) dsum += __shfl_xor(dsum, msk, 32);

    __shared__ float ls[16];
    if (lane == 0) {
        const float cf = cntC[c];                                   // count incl. self
        const float d = fmaxf(dsum - fexp2(sii), 1e-5f);            // exclude diagonal
        const float p = (dot - sii) * LN2;                          // matched sims, excl diag
        ls[wv] = ((cf - 1.f) * __logf(d) - p) / cf;
    }
    __syncthreads();
    if (tid == 0) {
        float s = 0.f;
#pragma unroll
        for (int i = 0; i < 16; ++i) s += ls[i];
        atomicAdd(out, s * (1.0f / M_ROWS));
    }
}

extern "C" void kernel_launch(void* const* d_in, const int* in_sizes, int n_in,
                              void* d_out, int out_size, void* d_ws, size_t ws_size,
                              hipStream_t stream) {
    (void)in_sizes; (void)n_in; (void)out_size; (void)ws_size;
    const float* feat = (const float*)d_in[0];
    const int* labels = (const int*)d_in[2];   // d_in[1] (ious) unused: coef == 1
    float* out = (float*)d_out;
    char* ws = (char*)d_ws;
    ushort* fnr = (ushort*)ws;                                  // 2 MB row-major bf16
    ushort* fnp = fnr + (size_t)M_ROWS * K_DIM;                 // 2 MB packed fragment-major
    float* denomP = (float*)(fnp + (size_t)M_ROWS * K_DIM);     // 32 x 8192 x 4B = 1 MB
    float* S = denomP + (size_t)NPAN * M_ROWS;                  // 30 KB
    float* cntC = S + NCLS * K_DIM;                             // 256 B
    float* slabS = cntC + 64;                                   // 128 x 30 KB
    float* slabC = slabS + (size_t)NSLAB * NCLS * K_DIM;        // 128 x 256 B

    knorm<<<M_ROWS / 16, 256, 0, stream>>>(feat, fnr, fnp);
    kclassp<<<NSLAB, 256, 0, stream>>>(fnr, labels, slabS, slabC);
    kreduce<<<31, 256, 0, stream>>>(slabS, slabC, S, cntC, out);
    kmain<<<528, 256, 0, stream>>>(fnp, denomP);
    kfin<<<M_ROWS / 16, 1024, 0, stream>>>(fnr, labels, denomP, S, cntC, out);
}

// Round 15
// 64.090 us; speedup vs baseline: 1.1550x; 1.1285x over previous
//
#include <hip/hip_runtime.h>
#include <hip/hip_bf16.h>

#define M_ROWS 8192
#define K_DIM 128
#define NCLS 60
#define NPAN 32            // 256-row/col panels; denomP has NPAN slots
#define NSIM 528           // 32*33/2 upper-triangle panel pairs
#define NSLAB 128          // class partial tables

// x = q_i . q_j where q = bf16(fhat * SCL), SCL^2 = 5*log2(e)  ->  sim = x*ln2, exp(sim) = 2^x
constexpr float SCL = 2.68579007f;     // sqrt(5 * 1.4426950408889634)
constexpr float LN2 = 0.69314718056f;

using f32x4 = __attribute__((ext_vector_type(4))) float;
using s16x8 = __attribute__((ext_vector_type(8))) short;

__device__ inline float bf2f(ushort u) {
    union { unsigned int i; float f; } v; v.i = ((unsigned int)u) << 16; return v.f;
}
__device__ inline float bfround(float x) {   // round f32 through bf16 (matches fnr/fnp)
    __hip_bfloat16 h = __float2bfloat16(x);
    return bf2f(*reinterpret_cast<const ushort*>(&h));
}
__device__ inline float fexp2(float x) {
#if __has_builtin(__builtin_amdgcn_exp2f)
    return __builtin_amdgcn_exp2f(x);
#else
    return exp2f(x);
#endif
}

// packed fragment-major layout: ushort index = c16*2048 + kk*512 + lane*8
//   (c16 = row/16 block, kk = k/32, lane = g*16+lrow; one MFMA fragment per 64-lane load)

// ---------------- K1: normalize -> fnr + fnp (512 blocks); class slabs on blocks<128 ----------------
__global__ __launch_bounds__(256) void kprep(const float* __restrict__ feat,
                                             const int* __restrict__ labels,
                                             ushort* __restrict__ fnr,
                                             ushort* __restrict__ fnp,
                                             float* __restrict__ slabS,
                                             float* __restrict__ slabC,
                                             float* __restrict__ out) {
    __shared__ ushort ln[16][128];
    __shared__ float Sl[NCLS * K_DIM];   // 30 KB
    __shared__ float Cl[NCLS];
    __shared__ int lab[64];
    const int tid = threadIdx.x, wv = tid >> 6, lane = tid & 63;

    // ---- part A: normalize rows blockIdx*16 .. +15 -> fnr + ln ----
    int row = wv * 4;
#pragma unroll
    for (int it = 0; it < 4; ++it, ++row) {
        const int grow = blockIdx.x * 16 + row;
        const float2 v = *(const float2*)&feat[(size_t)grow * K_DIM + lane * 2];
        float ss = v.x * v.x + v.y * v.y;
#pragma unroll
        for (int m = 1; m < 64; m <<= 1) ss += __shfl_xor(ss, m, 64);
        const float rs = rsqrtf(ss) * SCL;
        __hip_bfloat16 ha = __float2bfloat16(v.x * rs);
        __hip_bfloat16 hb = __float2bfloat16(v.y * rs);
        ushort2 o;
        o.x = *reinterpret_cast<const ushort*>(&ha);
        o.y = *reinterpret_cast<const ushort*>(&hb);
        *(ushort2*)&fnr[(size_t)grow * K_DIM + lane * 2] = o;
        *(ushort2*)&ln[row][lane * 2] = o;
    }
    __syncthreads();
    {   // packed fnp write
        const s16x8 vv = *(const s16x8*)&ln[tid & 15][(tid >> 4) * 8];
        *(s16x8*)&fnp[(size_t)blockIdx.x * 2048 + tid * 8] = vv;
    }
    if (blockIdx.x == 0 && tid == 0) out[0] = 0.f;

    // ---- part B (blocks < 128): class partials for rows 64b..+63, re-normalized from feat ----
    if (blockIdx.x < NSLAB) {
        const int rbase = blockIdx.x * 64;
        for (int i = tid; i < NCLS * K_DIM; i += 256) Sl[i] = 0.f;
        if (tid < NCLS) Cl[tid] = 0.f;
        if (tid < 64) lab[tid] = labels[rbase + tid];
        __syncthreads();

        const int rsub = tid >> 4;   // 16 rows concurrent (contiguous 16-lane groups)
        const int kc = tid & 15;     // 16 lanes x 8 f32 = 128 dims
#pragma unroll
        for (int it = 0; it < 4; ++it) {
            const int r = it * 16 + rsub;
            const int lb = lab[r];
            if (kc == 0) atomicAdd(&Cl[lb], 1.f);
            const f32x4 va = *(const f32x4*)&feat[(size_t)(rbase + r) * K_DIM + kc * 8];
            const f32x4 vb = *(const f32x4*)&feat[(size_t)(rbase + r) * K_DIM + kc * 8 + 4];
            float ss = va[0]*va[0] + va[1]*va[1] + va[2]*va[2] + va[3]*va[3]
                     + vb[0]*vb[0] + vb[1]*vb[1] + vb[2]*vb[2] + vb[3]*vb[3];
#pragma unroll
            for (int m = 1; m < 16; m <<= 1) ss += __shfl_xor(ss, m, 16);
            const float rs = rsqrtf(ss) * SCL;
            float* dst = &Sl[lb * K_DIM + kc * 8];
#pragma unroll
            for (int j = 0; j < 4; ++j) atomicAdd(&dst[j],     bfround(va[j] * rs));
#pragma unroll
            for (int j = 0; j < 4; ++j) atomicAdd(&dst[4 + j], bfround(vb[j] * rs));
        }
        __syncthreads();
        float* oS = slabS + (size_t)blockIdx.x * (NCLS * K_DIM);
        for (int i = tid; i < NCLS * K_DIM; i += 256) oS[i] = Sl[i];
        if (tid < NCLS) slabC[blockIdx.x * 64 + tid] = Cl[tid];
    }
}

// ---------------- K2: symmetric upper-tri panels (atomic-free) + slab reduce on blocks<31 ----------------
__global__ __launch_bounds__(256) void kmain(const ushort* __restrict__ fnp,
                                             const float* __restrict__ slabS,
                                             const float* __restrict__ slabC,
                                             float* __restrict__ denomP,
                                             float* __restrict__ S,
                                             float* __restrict__ cntC) {
    __shared__ float colbuf[4][256];   // 4 KB
    const int tid = threadIdx.x;
    const int lane = tid & 63;
    const int lrow = lane & 15;
    const int g = lane >> 4;
    const int wv = tid >> 6;

    // decode blockIdx.x -> (I, J), I <= J < 32; off(I) = 32I - I(I-1)/2
    const int bid = blockIdx.x;
    int I = (int)((65.0f - sqrtf(4225.0f - 8.0f * (float)bid)) * 0.5f);
    while ((I + 1) * 32 - ((I + 1) * I) / 2 <= bid) ++I;
    while (I * 32 - (I * (I - 1)) / 2 > bid) --I;
    const int J = I + (bid - (I * 32 - (I * (I - 1)) / 2));
    const bool offd = (J != I);
    const int rbase = I * 256 + wv * 64;

    // persistent A fragments: rows rbase..+63, K=128 (packed, lane-linear)
    s16x8 af[4][4];
#pragma unroll
    for (int m = 0; m < 4; ++m)
#pragma unroll
        for (int kk = 0; kk < 4; ++kk)
            af[m][kk] = *(const s16x8*)&fnp[(size_t)((rbase >> 4) + m) * 2048 + kk * 512 + lane * 8];

    float pd[4][4] = {};  // row partials across all 4 tiles

#pragma unroll
    for (int t = 0; t < 4; ++t) {   // 4 tiles of 64 cols = panel J
        const int c16b = J * 16 + t * 4;
        f32x4 acc[4][4] = {};
#pragma unroll
        for (int kk = 0; kk < 4; ++kk) {
            s16x8 bfr[4];
#pragma unroll
            for (int n = 0; n < 4; ++n)
                bfr[n] = *(const s16x8*)&fnp[(size_t)(c16b + n) * 2048 + kk * 512 + lane * 8];
#pragma unroll
            for (int m = 0; m < 4; ++m)
#pragma unroll
                for (int n = 0; n < 4; ++n)
                    acc[m][n] = __builtin_amdgcn_mfma_f32_16x16x32_bf16(af[m][kk], bfr[n], acc[m][n], 0, 0, 0);
        }
        float pcn[4] = {0.f, 0.f, 0.f, 0.f};
#pragma unroll
        for (int m = 0; m < 4; ++m)
#pragma unroll
            for (int n = 0; n < 4; ++n)
#pragma unroll
                for (int r = 0; r < 4; ++r) {
                    const float e = fexp2(acc[m][n][r]);
                    pd[m][r] += e;
                    pcn[n] += e;
                }
        if (offd) {
#pragma unroll
            for (int n = 0; n < 4; ++n) {
                float v = pcn[n];
                v += __shfl_xor(v, 16);
                v += __shfl_xor(v, 32);
                if (lane < 16) colbuf[wv][t * 64 + n * 16 + lrow] = v;
            }
        }
    }

    // row partials -> slot J, plain store (wave owns its rows)
#pragma unroll
    for (int m = 0; m < 4; ++m)
#pragma unroll
        for (int r = 0; r < 4; ++r) {
            float v = pd[m][r];
#pragma unroll
            for (int msk = 1; msk < 16; msk <<= 1) v += __shfl_xor(v, msk, 16);
            if (lrow == 0)
                denomP[(size_t)J * M_ROWS + rbase + m * 16 + g * 4 + r] = v;
        }

    // col partials: cross-wave LDS reduce -> slot I, plain store (block-uniform branch)
    if (offd) {
        __syncthreads();
        const float cv = colbuf[0][tid] + colbuf[1][tid] + colbuf[2][tid] + colbuf[3][tid];
        denomP[(size_t)I * M_ROWS + J * 256 + tid] = cv;
    }

    // tail: blocks 0-30 reduce slabs -> S, cntC (reads K1 outputs; kfin reads S next kernel)
    if (bid < 31) {
        const int i = bid * 256 + tid;
        if (i < NCLS * K_DIM) {
            float s = 0.f;
#pragma unroll 8
            for (int b = 0; b < NSLAB; ++b) s += slabS[(size_t)b * (NCLS * K_DIM) + i];
            S[i] = s;
        } else if (i < NCLS * K_DIM + NCLS) {
            const int c = i - NCLS * K_DIM;
            float s = 0.f;
#pragma unroll 8
            for (int b = 0; b < NSLAB; ++b) s += slabC[b * 64 + c];
            cntC[c] = s;
        }
    }
}

// ---------------- K3: finalize: per-row loss, mean ----------------
__global__ __launch_bounds__(1024) void kfin(const ushort* __restrict__ fn,
                                             const int* __restrict__ labels,
                                             const float* __restrict__ denomP,
                                             const float* __restrict__ S,
                                             const float* __restrict__ cntC,
                                             float* __restrict__ out) {
    const int tid = threadIdx.x;
    const int wv = tid >> 6, lane = tid & 63;
    const int row = blockIdx.x * 16 + wv;
    const ushort2 qv = *(const ushort2*)&fn[(size_t)row * K_DIM + lane * 2];
    const float f0 = bf2f(qv.x), f1 = bf2f(qv.y);
    const int c = labels[row];
    const float2 sv = *(const float2*)&S[c * K_DIM + lane * 2];
    float dot = f0 * sv.x + f1 * sv.y;   // q_i . S_c  (includes self)
    float sii = f0 * f0 + f1 * f1;       // q_i . q_i
#pragma unroll
    for (int msk = 1; msk < 64; msk <<= 1) {
        dot += __shfl_xor(dot, msk, 64);
        sii += __shfl_xor(sii, msk, 64);
    }
    // gather the 32 panel-slot partials for this row
    float dsum = (lane < NPAN) ? denomP[(size_t)lane * M_ROWS + row] : 0.f;
#pragma unroll
    for (int msk = 1; msk < 32; msk <<= 1) dsum += __shfl_xor(dsum, msk, 32);

    __shared__ float ls[16];
    if (lane == 0) {
        const float cf = cntC[c];                                   // count incl. self
        const float d = fmaxf(dsum - fexp2(sii), 1e-5f);            // exclude diagonal
        const float p = (dot - sii) * LN2;                          // matched sims, excl diag
        ls[wv] = ((cf - 1.f) * __logf(d) - p) / cf;
    }
    __syncthreads();
    if (tid == 0) {
        float s = 0.f;
#pragma unroll
        for (int i = 0; i < 16; ++i) s += ls[i];
        atomicAdd(out, s * (1.0f / M_ROWS));
    }
}

extern "C" void kernel_launch(void* const* d_in, const int* in_sizes, int n_in,
                              void* d_out, int out_size, void* d_ws, size_t ws_size,
                              hipStream_t stream) {
    (void)in_sizes; (void)n_in; (void)out_size; (void)ws_size;
    const float* feat = (const float*)d_in[0];
    const int* labels = (const int*)d_in[2];   // d_in[1] (ious) unused: coef == 1
    float* out = (float*)d_out;
    char* ws = (char*)d_ws;
    ushort* fnr = (ushort*)ws;                                  // 2 MB row-major bf16
    ushort* fnp = fnr + (size_t)M_ROWS * K_DIM;                 // 2 MB packed fragment-major
    float* denomP = (float*)(fnp + (size_t)M_ROWS * K_DIM);     // 32 x 8192 x 4B = 1 MB
    float* S = denomP + (size_t)NPAN * M_ROWS;                  // 30 KB
    float* cntC = S + NCLS * K_DIM;                             // 256 B
    float* slabS = cntC + 64;                                   // 128 x 30 KB
    float* slabC = slabS + (size_t)NSLAB * NCLS * K_DIM;        // 128 x 256 B

    kprep<<<M_ROWS / 16, 256, 0, stream>>>(feat, labels, fnr, fnp, slabS, slabC, out);
    kmain<<<NSIM, 256, 0, stream>>>(fnp, slabS, slabC, denomP, S, cntC);
    kfin<<<M_ROWS / 16, 1024, 0, stream>>>(fnr, labels, denomP, S, cntC, out);
}

// Round 16
// 62.388 us; speedup vs baseline: 1.1866x; 1.0273x over previous
//
#include <hip/hip_runtime.h>
#include <hip/hip_bf16.h>

#define M_ROWS 8192
#define K_DIM 128
#define NCLS 60
#define NPAN 32            // 256-row/col panels; denomP has NPAN slots
#define NSIM 528           // 32*33/2 upper-triangle panel pairs
#define NSLAB 128          // class partial tables

// x = q_i . q_j where q = bf16(fhat * SCL), SCL^2 = 5*log2(e)  ->  sim = x*ln2, exp(sim) = 2^x
constexpr float SCL = 2.68579007f;     // sqrt(5 * 1.4426950408889634)
constexpr float LN2 = 0.69314718056f;

using f32x4 = __attribute__((ext_vector_type(4))) float;
using s16x8 = __attribute__((ext_vector_type(8))) short;

__device__ inline float bf2f(ushort u) {
    union { unsigned int i; float f; } v; v.i = ((unsigned int)u) << 16; return v.f;
}
__device__ inline float bfround(float x) {   // round f32 through bf16 (matches fnr/fnp)
    __hip_bfloat16 h = __float2bfloat16(x);
    return bf2f(*reinterpret_cast<const ushort*>(&h));
}
__device__ inline float fexp2(float x) {
#if __has_builtin(__builtin_amdgcn_exp2f)
    return __builtin_amdgcn_exp2f(x);
#else
    return exp2f(x);
#endif
}

// packed fragment-major layout: ushort index = c16*2048 + kk*512 + lane*8
//   (c16 = row/16 block, kk = k/32, lane = g*16+lrow; one MFMA fragment per 64-lane load)

// ---------------- K1: normalize -> fnr + fnp (512 blocks); class slabs on blocks<128 ----------------
__global__ __launch_bounds__(256) void kprep(const float* __restrict__ feat,
                                             const int* __restrict__ labels,
                                             ushort* __restrict__ fnr,
                                             ushort* __restrict__ fnp,
                                             float* __restrict__ slabS,
                                             float* __restrict__ slabC,
                                             float* __restrict__ out) {
    __shared__ ushort ln[16][128];
    __shared__ float Sl[NCLS * K_DIM];   // 30 KB
    __shared__ float Cl[NCLS];
    __shared__ int lab[64];
    const int tid = threadIdx.x, wv = tid >> 6, lane = tid & 63;

    // ---- part A: normalize rows blockIdx*16 .. +15 -> fnr + ln ----
    int row = wv * 4;
#pragma unroll
    for (int it = 0; it < 4; ++it, ++row) {
        const int grow = blockIdx.x * 16 + row;
        const float2 v = *(const float2*)&feat[(size_t)grow * K_DIM + lane * 2];
        float ss = v.x * v.x + v.y * v.y;
#pragma unroll
        for (int m = 1; m < 64; m <<= 1) ss += __shfl_xor(ss, m, 64);
        const float rs = rsqrtf(ss) * SCL;
        __hip_bfloat16 ha = __float2bfloat16(v.x * rs);
        __hip_bfloat16 hb = __float2bfloat16(v.y * rs);
        ushort2 o;
        o.x = *reinterpret_cast<const ushort*>(&ha);
        o.y = *reinterpret_cast<const ushort*>(&hb);
        *(ushort2*)&fnr[(size_t)grow * K_DIM + lane * 2] = o;
        *(ushort2*)&ln[row][lane * 2] = o;
    }
    __syncthreads();
    {   // packed fnp write
        const s16x8 vv = *(const s16x8*)&ln[tid & 15][(tid >> 4) * 8];
        *(s16x8*)&fnp[(size_t)blockIdx.x * 2048 + tid * 8] = vv;
    }
    if (blockIdx.x == 0 && tid == 0) out[0] = 0.f;

    // ---- part B (blocks < 128): class partials for rows 64b..+63, re-normalized from feat ----
    if (blockIdx.x < NSLAB) {
        const int rbase = blockIdx.x * 64;
        for (int i = tid; i < NCLS * K_DIM; i += 256) Sl[i] = 0.f;
        if (tid < NCLS) Cl[tid] = 0.f;
        if (tid < 64) lab[tid] = labels[rbase + tid];
        __syncthreads();

        const int rsub = tid >> 4;   // 16 rows concurrent (contiguous 16-lane groups)
        const int kc = tid & 15;     // 16 lanes x 8 f32 = 128 dims
#pragma unroll
        for (int it = 0; it < 4; ++it) {
            const int r = it * 16 + rsub;
            const int lb = lab[r];
            if (kc == 0) atomicAdd(&Cl[lb], 1.f);
            const f32x4 va = *(const f32x4*)&feat[(size_t)(rbase + r) * K_DIM + kc * 8];
            const f32x4 vb = *(const f32x4*)&feat[(size_t)(rbase + r) * K_DIM + kc * 8 + 4];
            float ss = va[0]*va[0] + va[1]*va[1] + va[2]*va[2] + va[3]*va[3]
                     + vb[0]*vb[0] + vb[1]*vb[1] + vb[2]*vb[2] + vb[3]*vb[3];
#pragma unroll
            for (int m = 1; m < 16; m <<= 1) ss += __shfl_xor(ss, m, 16);
            const float rs = rsqrtf(ss) * SCL;
            float* dst = &Sl[lb * K_DIM + kc * 8];
#pragma unroll
            for (int j = 0; j < 4; ++j) atomicAdd(&dst[j],     bfround(va[j] * rs));
#pragma unroll
            for (int j = 0; j < 4; ++j) atomicAdd(&dst[4 + j], bfround(vb[j] * rs));
        }
        __syncthreads();
        float* oS = slabS + (size_t)blockIdx.x * (NCLS * K_DIM);
        for (int i = tid; i < NCLS * K_DIM; i += 256) oS[i] = Sl[i];
        if (tid < NCLS) slabC[blockIdx.x * 64 + tid] = Cl[tid];
    }
}

// ---------------- K2: symmetric upper-tri panels, software-pipelined B loads ----------------
__global__ __launch_bounds__(256) void kmain(const ushort* __restrict__ fnp,
                                             const float* __restrict__ slabS,
                                             const float* __restrict__ slabC,
                                             float* __restrict__ denomP,
                                             float* __restrict__ S,
                                             float* __restrict__ cntC) {
    __shared__ float colbuf[4][256];   // 4 KB
    const int tid = threadIdx.x;
    const int lane = tid & 63;
    const int lrow = lane & 15;
    const int g = lane >> 4;
    const int wv = tid >> 6;

    // decode blockIdx.x -> (I, J), I <= J < 32; off(I) = 32I - I(I-1)/2
    const int bid = blockIdx.x;
    int I = (int)((65.0f - sqrtf(4225.0f - 8.0f * (float)bid)) * 0.5f);
    while ((I + 1) * 32 - ((I + 1) * I) / 2 <= bid) ++I;
    while (I * 32 - (I * (I - 1)) / 2 > bid) --I;
    const int J = I + (bid - (I * 32 - (I * (I - 1)) / 2));
    const bool offd = (J != I);
    const int rbase = I * 256 + wv * 64;

    // persistent A fragments: rows rbase..+63, K=128 (packed, lane-linear)
    s16x8 af[4][4];
#pragma unroll
    for (int m = 0; m < 4; ++m)
#pragma unroll
        for (int kk = 0; kk < 4; ++kk)
            af[m][kk] = *(const s16x8*)&fnp[(size_t)((rbase >> 4) + m) * 2048 + kk * 512 + lane * 8];

    float pd[4][4] = {};  // row partials across all 4 tiles

    // rotating B prefetch buffer: holds the NEXT kk-stage's 4 fragments
    s16x8 bq[4];
#pragma unroll
    for (int n = 0; n < 4; ++n)
        bq[n] = *(const s16x8*)&fnp[(size_t)(J * 16 + n) * 2048 + lane * 8];   // t=0, kk=0

#pragma unroll
    for (int t = 0; t < 4; ++t) {   // 4 tiles of 64 cols = panel J
        const int c16b = J * 16 + t * 4;
        f32x4 acc[4][4] = {};
#pragma unroll
        for (int kk = 0; kk < 4; ++kk) {
            s16x8 bc[4];
#pragma unroll
            for (int n = 0; n < 4; ++n) bc[n] = bq[n];
            // issue the next stage's loads before consuming this stage
            if (kk < 3) {
#pragma unroll
                for (int n = 0; n < 4; ++n)
                    bq[n] = *(const s16x8*)&fnp[(size_t)(c16b + n) * 2048 + (kk + 1) * 512 + lane * 8];
            } else if (t < 3) {
#pragma unroll
                for (int n = 0; n < 4; ++n)
                    bq[n] = *(const s16x8*)&fnp[(size_t)(c16b + 4 + n) * 2048 + lane * 8];
            }
#pragma unroll
            for (int m = 0; m < 4; ++m)
#pragma unroll
                for (int n = 0; n < 4; ++n)
                    acc[m][n] = __builtin_amdgcn_mfma_f32_16x16x32_bf16(af[m][kk], bc[n], acc[m][n], 0, 0, 0);
        }
        // exp2 phase (~500 trans/VALU cyc) covers the next tile's L2 latency
        float pcn[4] = {0.f, 0.f, 0.f, 0.f};
#pragma unroll
        for (int m = 0; m < 4; ++m)
#pragma unroll
            for (int n = 0; n < 4; ++n)
#pragma unroll
                for (int r = 0; r < 4; ++r) {
                    const float e = fexp2(acc[m][n][r]);
                    pd[m][r] += e;
                    pcn[n] += e;
                }
        if (offd) {
#pragma unroll
            for (int n = 0; n < 4; ++n) {
                float v = pcn[n];
                v += __shfl_xor(v, 16);
                v += __shfl_xor(v, 32);
                if (lane < 16) colbuf[wv][t * 64 + n * 16 + lrow] = v;
            }
        }
    }

    // row partials -> slot J, plain store (wave owns its rows)
#pragma unroll
    for (int m = 0; m < 4; ++m)
#pragma unroll
        for (int r = 0; r < 4; ++r) {
            float v = pd[m][r];
#pragma unroll
            for (int msk = 1; msk < 16; msk <<= 1) v += __shfl_xor(v, msk, 16);
            if (lrow == 0)
                denomP[(size_t)J * M_ROWS + rbase + m * 16 + g * 4 + r] = v;
        }

    // col partials: cross-wave LDS reduce -> slot I, plain store (block-uniform branch)
    if (offd) {
        __syncthreads();
        const float cv = colbuf[0][tid] + colbuf[1][tid] + colbuf[2][tid] + colbuf[3][tid];
        denomP[(size_t)I * M_ROWS + J * 256 + tid] = cv;
    }

    // tail: blocks 0-30 reduce slabs -> S, cntC (reads K1 outputs; kfin reads S next kernel)
    if (bid < 31) {
        const int i = bid * 256 + tid;
        if (i < NCLS * K_DIM) {
            float s = 0.f;
#pragma unroll 8
            for (int b = 0; b < NSLAB; ++b) s += slabS[(size_t)b * (NCLS * K_DIM) + i];
            S[i] = s;
        } else if (i < NCLS * K_DIM + NCLS) {
            const int c = i - NCLS * K_DIM;
            float s = 0.f;
#pragma unroll 8
            for (int b = 0; b < NSLAB; ++b) s += slabC[b * 64 + c];
            cntC[c] = s;
        }
    }
}

// ---------------- K3: finalize: per-row loss, mean ----------------
__global__ __launch_bounds__(1024) void kfin(const ushort* __restrict__ fn,
                                             const int* __restrict__ labels,
                                             const float* __restrict__ denomP,
                                             const float* __restrict__ S,
                                             const float* __restrict__ cntC,
                                             float* __restrict__ out) {
    const int tid = threadIdx.x;
    const int wv = tid >> 6, lane = tid & 63;
    const int row = blockIdx.x * 16 + wv;
    const ushort2 qv = *(const ushort2*)&fn[(size_t)row * K_DIM + lane * 2];
    const float f0 = bf2f(qv.x), f1 = bf2f(qv.y);
    const int c = labels[row];
    const float2 sv = *(const float2*)&S[c * K_DIM + lane * 2];
    float dot = f0 * sv.x + f1 * sv.y;   // q_i . S_c  (includes self)
    float sii = f0 * f0 + f1 * f1;       // q_i . q_i
#pragma unroll
    for (int msk = 1; msk < 64; msk <<= 1) {
        dot += __shfl_xor(dot, msk, 64);
        sii += __shfl_xor(sii, msk, 64);
    }
    // gather the 32 panel-slot partials for this row
    float dsum = (lane < NPAN) ? denomP[(size_t)lane * M_ROWS + row] : 0.f;
#pragma unroll
    for (int msk = 1; msk < 32; msk <<= 1) dsum += __shfl_xor(dsum, msk, 32);

    __shared__ float ls[16];
    if (lane == 0) {
        const float cf = cntC[c];                                   // count incl. self
        const float d = fmaxf(dsum - fexp2(sii), 1e-5f);            // exclude diagonal
        const float p = (dot - sii) * LN2;                          // matched sims, excl diag
        ls[wv] = ((cf - 1.f) * __logf(d) - p) / cf;
    }
    __syncthreads();
    if (tid == 0) {
        float s = 0.f;
#pragma unroll
        for (int i = 0; i < 16; ++i) s += ls[i];
        atomicAdd(out, s * (1.0f / M_ROWS));
    }
}

extern "C" void kernel_launch(void* const* d_in, const int* in_sizes, int n_in,
                              void* d_out, int out_size, void* d_ws, size_t ws_size,
                              hipStream_t stream) {
    (void)in_sizes; (void)n_in; (void)out_size; (void)ws_size;
    const float* feat = (const float*)d_in[0];
    const int* labels = (const int*)d_in[2];   // d_in[1] (ious) unused: coef == 1
    float* out = (float*)d_out;
    char* ws = (char*)d_ws;
    ushort* fnr = (ushort*)ws;                                  // 2 MB row-major bf16
    ushort* fnp = fnr + (size_t)M_ROWS * K_DIM;                 // 2 MB packed fragment-major
    float* denomP = (float*)(fnp + (size_t)M_ROWS * K_DIM);     // 32 x 8192 x 4B = 1 MB
    float* S = denomP + (size_t)NPAN * M_ROWS;                  // 30 KB
    float* cntC = S + NCLS * K_DIM;                             // 256 B
    float* slabS = cntC + 64;                                   // 128 x 30 KB
    float* slabC = slabS + (size_t)NSLAB * NCLS * K_DIM;        // 128 x 256 B

    kprep<<<M_ROWS / 16, 256, 0, stream>>>(feat, labels, fnr, fnp, slabS, slabC, out);
    kmain<<<NSIM, 256, 0, stream>>>(fnp, slabS, slabC, denomP, S, cntC);
    kfin<<<M_ROWS / 16, 1024, 0, stream>>>(fnr, labels, denomP, S, cntC, out);
}

// Round 17
// 58.030 us; speedup vs baseline: 1.2757x; 1.0751x over previous
//
#include <hip/hip_runtime.h>
#include <hip/hip_bf16.h>

#define M_ROWS 8192
#define K_DIM 128
#define NCLS 60
#define NPAN 32            // 256-row/col panels; denomP has NPAN slots
#define NSIM 528           // 32*33/2 upper-triangle panel pairs
#define NSLAB 128          // class partial tables

// x = q_i . q_j where q = bf16(fhat * SCL), SCL^2 = 5*log2(e)  ->  sim = x*ln2, exp(sim) = 2^x
constexpr float SCL = 2.68579007f;     // sqrt(5 * 1.4426950408889634)
constexpr float LN2 = 0.69314718056f;

using f32x4 = __attribute__((ext_vector_type(4))) float;
using s16x8 = __attribute__((ext_vector_type(8))) short;

__device__ inline float bf2f(ushort u) {
    union { unsigned int i; float f; } v; v.i = ((unsigned int)u) << 16; return v.f;
}
__device__ inline float bfround(float x) {   // round f32 through bf16 (matches fnr/fnp)
    __hip_bfloat16 h = __float2bfloat16(x);
    return bf2f(*reinterpret_cast<const ushort*>(&h));
}
__device__ inline float fexp2(float x) {
#if __has_builtin(__builtin_amdgcn_exp2f)
    return __builtin_amdgcn_exp2f(x);
#else
    return exp2f(x);
#endif
}

// packed fragment-major layout: ushort index = c16*2048 + kk*512 + lane*8
//   (c16 = row/16 block, kk = k/32, lane = g*16+lrow; one MFMA fragment per 64-lane load)

// ---------------- K1: normalize -> fnr + fnp (512 blocks); class slabs on blocks<128 ----------------
__global__ __launch_bounds__(256) void kprep(const float* __restrict__ feat,
                                             const int* __restrict__ labels,
                                             ushort* __restrict__ fnr,
                                             ushort* __restrict__ fnp,
                                             float* __restrict__ slabS,
                                             float* __restrict__ slabC,
                                             float* __restrict__ out) {
    __shared__ ushort ln[16][128];
    __shared__ float Sl[NCLS * K_DIM];   // 30 KB
    __shared__ float Cl[NCLS];
    __shared__ int lab[64];
    const int tid = threadIdx.x, wv = tid >> 6, lane = tid & 63;

    // ---- part A: normalize rows blockIdx*16 .. +15 -> fnr + ln ----
    int row = wv * 4;
#pragma unroll
    for (int it = 0; it < 4; ++it, ++row) {
        const int grow = blockIdx.x * 16 + row;
        const float2 v = *(const float2*)&feat[(size_t)grow * K_DIM + lane * 2];
        float ss = v.x * v.x + v.y * v.y;
#pragma unroll
        for (int m = 1; m < 64; m <<= 1) ss += __shfl_xor(ss, m, 64);
        const float rs = rsqrtf(ss) * SCL;
        __hip_bfloat16 ha = __float2bfloat16(v.x * rs);
        __hip_bfloat16 hb = __float2bfloat16(v.y * rs);
        ushort2 o;
        o.x = *reinterpret_cast<const ushort*>(&ha);
        o.y = *reinterpret_cast<const ushort*>(&hb);
        *(ushort2*)&fnr[(size_t)grow * K_DIM + lane * 2] = o;
        *(ushort2*)&ln[row][lane * 2] = o;
    }
    __syncthreads();
    {   // packed fnp write
        const s16x8 vv = *(const s16x8*)&ln[tid & 15][(tid >> 4) * 8];
        *(s16x8*)&fnp[(size_t)blockIdx.x * 2048 + tid * 8] = vv;
    }
    if (blockIdx.x == 0 && tid == 0) out[0] = 0.f;

    // ---- part B (blocks < 128): class partials for rows 64b..+63, re-normalized from feat ----
    if (blockIdx.x < NSLAB) {
        const int rbase = blockIdx.x * 64;
        for (int i = tid; i < NCLS * K_DIM; i += 256) Sl[i] = 0.f;
        if (tid < NCLS) Cl[tid] = 0.f;
        if (tid < 64) lab[tid] = labels[rbase + tid];
        __syncthreads();

        const int rsub = tid >> 4;   // 16 rows concurrent (contiguous 16-lane groups)
        const int kc = tid & 15;     // 16 lanes x 8 f32 = 128 dims
#pragma unroll
        for (int it = 0; it < 4; ++it) {
            const int r = it * 16 + rsub;
            const int lb = lab[r];
            if (kc == 0) atomicAdd(&Cl[lb], 1.f);
            const f32x4 va = *(const f32x4*)&feat[(size_t)(rbase + r) * K_DIM + kc * 8];
            const f32x4 vb = *(const f32x4*)&feat[(size_t)(rbase + r) * K_DIM + kc * 8 + 4];
            float ss = va[0]*va[0] + va[1]*va[1] + va[2]*va[2] + va[3]*va[3]
                     + vb[0]*vb[0] + vb[1]*vb[1] + vb[2]*vb[2] + vb[3]*vb[3];
#pragma unroll
            for (int m = 1; m < 16; m <<= 1) ss += __shfl_xor(ss, m, 16);
            const float rs = rsqrtf(ss) * SCL;
            float* dst = &Sl[lb * K_DIM + kc * 8];
#pragma unroll
            for (int j = 0; j < 4; ++j) atomicAdd(&dst[j],     bfround(va[j] * rs));
#pragma unroll
            for (int j = 0; j < 4; ++j) atomicAdd(&dst[4 + j], bfround(vb[j] * rs));
        }
        __syncthreads();
        float* oS = slabS + (size_t)blockIdx.x * (NCLS * K_DIM);
        for (int i = tid; i < NCLS * K_DIM; i += 256) oS[i] = Sl[i];
        if (tid < NCLS) slabC[blockIdx.x * 64 + tid] = Cl[tid];
    }
}

// ---------------- K2: symmetric upper-tri panels, 8 waves x 32 rows (occupancy) ----------------
__global__ __launch_bounds__(512) void kmain(const ushort* __restrict__ fnp,
                                             const float* __restrict__ slabS,
                                             const float* __restrict__ slabC,
                                             float* __restrict__ denomP,
                                             float* __restrict__ S,
                                             float* __restrict__ cntC) {
    __shared__ float colbuf[8][256];   // 8 KB
    const int tid = threadIdx.x;
    const int lane = tid & 63;
    const int lrow = lane & 15;
    const int g = lane >> 4;
    const int wv = tid >> 6;           // 0..7

    // decode blockIdx.x -> (I, J), I <= J < 32; off(I) = 32I - I(I-1)/2
    const int bid = blockIdx.x;
    int I = (int)((65.0f - sqrtf(4225.0f - 8.0f * (float)bid)) * 0.5f);
    while ((I + 1) * 32 - ((I + 1) * I) / 2 <= bid) ++I;
    while (I * 32 - (I * (I - 1)) / 2 > bid) --I;
    const int J = I + (bid - (I * 32 - (I * (I - 1)) / 2));
    const bool offd = (J != I);
    const int rbase = I * 256 + wv * 32;   // this wave's 32 rows

    // persistent A fragments: rows rbase..+31, K=128 (packed, lane-linear)
    s16x8 af[2][4];
#pragma unroll
    for (int m = 0; m < 2; ++m)
#pragma unroll
        for (int kk = 0; kk < 4; ++kk)
            af[m][kk] = *(const s16x8*)&fnp[(size_t)((rbase >> 4) + m) * 2048 + kk * 512 + lane * 8];

    float pd[2][4] = {};  // row partials across all 4 tiles

#pragma unroll
    for (int t = 0; t < 4; ++t) {   // 4 tiles of 64 cols = panel J
        const int c16b = J * 16 + t * 4;
        f32x4 acc[2][4] = {};
#pragma unroll
        for (int kk = 0; kk < 4; ++kk) {
            s16x8 bfr[4];
#pragma unroll
            for (int n = 0; n < 4; ++n)
                bfr[n] = *(const s16x8*)&fnp[(size_t)(c16b + n) * 2048 + kk * 512 + lane * 8];
#pragma unroll
            for (int m = 0; m < 2; ++m)
#pragma unroll
                for (int n = 0; n < 4; ++n)
                    acc[m][n] = __builtin_amdgcn_mfma_f32_16x16x32_bf16(af[m][kk], bfr[n], acc[m][n], 0, 0, 0);
        }
        float pcn[4] = {0.f, 0.f, 0.f, 0.f};
#pragma unroll
        for (int m = 0; m < 2; ++m)
#pragma unroll
            for (int n = 0; n < 4; ++n)
#pragma unroll
                for (int r = 0; r < 4; ++r) {
                    const float e = fexp2(acc[m][n][r]);
                    pd[m][r] += e;
                    pcn[n] += e;
                }
        if (offd) {
#pragma unroll
            for (int n = 0; n < 4; ++n) {
                float v = pcn[n];
                v += __shfl_xor(v, 16);
                v += __shfl_xor(v, 32);
                if (lane < 16) colbuf[wv][t * 64 + n * 16 + lrow] = v;
            }
        }
    }

    // row partials -> slot J, plain store (wave owns its rows)
#pragma unroll
    for (int m = 0; m < 2; ++m)
#pragma unroll
        for (int r = 0; r < 4; ++r) {
            float v = pd[m][r];
#pragma unroll
            for (int msk = 1; msk < 16; msk <<= 1) v += __shfl_xor(v, msk, 16);
            if (lrow == 0)
                denomP[(size_t)J * M_ROWS + rbase + m * 16 + g * 4 + r] = v;
        }

    // col partials: cross-wave LDS reduce -> slot I, plain store (block-uniform branch)
    if (offd) {
        __syncthreads();
        if (tid < 256) {
            float cv = 0.f;
#pragma unroll
            for (int w = 0; w < 8; ++w) cv += colbuf[w][tid];
            denomP[(size_t)I * M_ROWS + J * 256 + tid] = cv;
        }
    }

    // tail: blocks 0-30 reduce slabs -> S, cntC (reads K1 outputs; kfin reads S next kernel)
    if (bid < 31 && tid < 256) {
        const int i = bid * 256 + tid;
        if (i < NCLS * K_DIM) {
            float s = 0.f;
#pragma unroll 8
            for (int b = 0; b < NSLAB; ++b) s += slabS[(size_t)b * (NCLS * K_DIM) + i];
            S[i] = s;
        } else if (i < NCLS * K_DIM + NCLS) {
            const int c = i - NCLS * K_DIM;
            float s = 0.f;
#pragma unroll 8
            for (int b = 0; b < NSLAB; ++b) s += slabC[b * 64 + c];
            cntC[c] = s;
        }
    }
}

// ---------------- K3: finalize: per-row loss, mean ----------------
__global__ __launch_bounds__(1024) void kfin(const ushort* __restrict__ fn,
                                             const int* __restrict__ labels,
                                             const float* __restrict__ denomP,
                                             const float* __restrict__ S,
                                             const float* __restrict__ cntC,
                                             float* __restrict__ out) {
    const int tid = threadIdx.x;
    const int wv = tid >> 6, lane = tid & 63;
    const int row = blockIdx.x * 16 + wv;
    const ushort2 qv = *(const ushort2*)&fn[(size_t)row * K_DIM + lane * 2];
    const float f0 = bf2f(qv.x), f1 = bf2f(qv.y);
    const int c = labels[row];
    const float2 sv = *(const float2*)&S[c * K_DIM + lane * 2];
    float dot = f0 * sv.x + f1 * sv.y;   // q_i . S_c  (includes self)
    float sii = f0 * f0 + f1 * f1;       // q_i . q_i
#pragma unroll
    for (int msk = 1; msk < 64; msk <<= 1) {
        dot += __shfl_xor(dot, msk, 64);
        sii += __shfl_xor(sii, msk, 64);
    }
    // gather the 32 panel-slot partials for this row
    float dsum = (lane < NPAN) ? denomP[(size_t)lane * M_ROWS + row] : 0.f;
#pragma unroll
    for (int msk = 1; msk < 32; msk <<= 1) dsum += __shfl_xor(dsum, msk, 32);

    __shared__ float ls[16];
    if (lane == 0) {
        const float cf = cntC[c];                                   // count incl. self
        const float d = fmaxf(dsum - fexp2(sii), 1e-5f);            // exclude diagonal
        const float p = (dot - sii) * LN2;                          // matched sims, excl diag
        ls[wv] = ((cf - 1.f) * __logf(d) - p) / cf;
    }
    __syncthreads();
    if (tid == 0) {
        float s = 0.f;
#pragma unroll
        for (int i = 0; i < 16; ++i) s += ls[i];
        atomicAdd(out, s * (1.0f / M_ROWS));
    }
}

extern "C" void kernel_launch(void* const* d_in, const int* in_sizes, int n_in,
                              void* d_out, int out_size, void* d_ws, size_t ws_size,
                              hipStream_t stream) {
    (void)in_sizes; (void)n_in; (void)out_size; (void)ws_size;
    const float* feat = (const float*)d_in[0];
    const int* labels = (const int*)d_in[2];   // d_in[1] (ious) unused: coef == 1
    float* out = (float*)d_out;
    char* ws = (char*)d_ws;
    ushort* fnr = (ushort*)ws;                                  // 2 MB row-major bf16
    ushort* fnp = fnr + (size_t)M_ROWS * K_DIM;                 // 2 MB packed fragment-major
    float* denomP = (float*)(fnp + (size_t)M_ROWS * K_DIM);     // 32 x 8192 x 4B = 1 MB
    float* S = denomP + (size_t)NPAN * M_ROWS;                  // 30 KB
    float* cntC = S + NCLS * K_DIM;                             // 256 B
    float* slabS = cntC + 64;                                   // 128 x 30 KB
    float* slabC = slabS + (size_t)NSLAB * NCLS * K_DIM;        // 128 x 256 B

    kprep<<<M_ROWS / 16, 256, 0, stream>>>(feat, labels, fnr, fnp, slabS, slabC, out);
    kmain<<<NSIM, 512, 0, stream>>>(fnp, slabS, slabC, denomP, S, cntC);
    kfin<<<M_ROWS / 16, 1024, 0, stream>>>(fnr, labels, denomP, S, cntC, out);
}

// Round 18
// 56.135 us; speedup vs baseline: 1.3187x; 1.0338x over previous
//
#include <hip/hip_runtime.h>
#include <hip/hip_bf16.h>

#define M_ROWS 8192
#define K_DIM 128
#define NCLS 60
#define NPAN 32            // 256-row/col panels; denomP has NPAN slots
#define NSIM 528           // 32*33/2 upper-triangle panel pairs
#define NSLAB 128          // class partial tables

// x = q_i . q_j where q = bf16(fhat * SCL), SCL^2 = 5*log2(e)  ->  sim = x*ln2, exp(sim) = 2^x
constexpr float SCL = 2.68579007f;     // sqrt(5 * 1.4426950408889634)
constexpr float LN2 = 0.69314718056f;

using f32x4 = __attribute__((ext_vector_type(4))) float;
using s16x8 = __attribute__((ext_vector_type(8))) short;

__device__ inline float bf2f(ushort u) {
    union { unsigned int i; float f; } v; v.i = ((unsigned int)u) << 16; return v.f;
}
__device__ inline float bfround(float x) {   // round f32 through bf16 (matches fnr/fnp)
    __hip_bfloat16 h = __float2bfloat16(x);
    return bf2f(*reinterpret_cast<const ushort*>(&h));
}
__device__ inline float fexp2(float x) {
#if __has_builtin(__builtin_amdgcn_exp2f)
    return __builtin_amdgcn_exp2f(x);
#else
    return exp2f(x);
#endif
}

// packed fragment-major layout: ushort index = c16*2048 + kk*512 + lane*8
//   (c16 = row/16 block, kk = k/32, lane = g*16+lrow; one MFMA fragment per 64-lane load)

// ---------------- K1: normalize -> fnr + fnp (512 blocks); class slabs on blocks<128 ----------------
__global__ __launch_bounds__(256) void kprep(const float* __restrict__ feat,
                                             const int* __restrict__ labels,
                                             ushort* __restrict__ fnr,
                                             ushort* __restrict__ fnp,
                                             float* __restrict__ slabS,
                                             float* __restrict__ slabC,
                                             float* __restrict__ out) {
    __shared__ ushort ln[16][128];
    __shared__ float Sl[NCLS * K_DIM];   // 30 KB
    __shared__ float Cl[NCLS];
    __shared__ int lab[64];
    const int tid = threadIdx.x, wv = tid >> 6, lane = tid & 63;

    // ---- part A: normalize rows blockIdx*16 .. +15 -> fnr + ln ----
    int row = wv * 4;
#pragma unroll
    for (int it = 0; it < 4; ++it, ++row) {
        const int grow = blockIdx.x * 16 + row;
        const float2 v = *(const float2*)&feat[(size_t)grow * K_DIM + lane * 2];
        float ss = v.x * v.x + v.y * v.y;
#pragma unroll
        for (int m = 1; m < 64; m <<= 1) ss += __shfl_xor(ss, m, 64);
        const float rs = rsqrtf(ss) * SCL;
        __hip_bfloat16 ha = __float2bfloat16(v.x * rs);
        __hip_bfloat16 hb = __float2bfloat16(v.y * rs);
        ushort2 o;
        o.x = *reinterpret_cast<const ushort*>(&ha);
        o.y = *reinterpret_cast<const ushort*>(&hb);
        *(ushort2*)&fnr[(size_t)grow * K_DIM + lane * 2] = o;
        *(ushort2*)&ln[row][lane * 2] = o;
    }
    __syncthreads();
    {   // packed fnp write
        const s16x8 vv = *(const s16x8*)&ln[tid & 15][(tid >> 4) * 8];
        *(s16x8*)&fnp[(size_t)blockIdx.x * 2048 + tid * 8] = vv;
    }
    if (blockIdx.x == 0 && tid == 0) out[0] = 0.f;

    // ---- part B (blocks < 128): class partials for rows 64b..+63, re-normalized from feat ----
    if (blockIdx.x < NSLAB) {
        const int rbase = blockIdx.x * 64;
        for (int i = tid; i < NCLS * K_DIM; i += 256) Sl[i] = 0.f;
        if (tid < NCLS) Cl[tid] = 0.f;
        if (tid < 64) lab[tid] = labels[rbase + tid];
        __syncthreads();

        const int rsub = tid >> 4;   // 16 rows concurrent (contiguous 16-lane groups)
        const int kc = tid & 15;     // 16 lanes x 8 f32 = 128 dims
#pragma unroll
        for (int it = 0; it < 4; ++it) {
            const int r = it * 16 + rsub;
            const int lb = lab[r];
            if (kc == 0) atomicAdd(&Cl[lb], 1.f);
            const f32x4 va = *(const f32x4*)&feat[(size_t)(rbase + r) * K_DIM + kc * 8];
            const f32x4 vb = *(const f32x4*)&feat[(size_t)(rbase + r) * K_DIM + kc * 8 + 4];
            float ss = va[0]*va[0] + va[1]*va[1] + va[2]*va[2] + va[3]*va[3]
                     + vb[0]*vb[0] + vb[1]*vb[1] + vb[2]*vb[2] + vb[3]*vb[3];
#pragma unroll
            for (int m = 1; m < 16; m <<= 1) ss += __shfl_xor(ss, m, 16);
            const float rs = rsqrtf(ss) * SCL;
            float* dst = &Sl[lb * K_DIM + kc * 8];
#pragma unroll
            for (int j = 0; j < 4; ++j) atomicAdd(&dst[j],     bfround(va[j] * rs));
#pragma unroll
            for (int j = 0; j < 4; ++j) atomicAdd(&dst[4 + j], bfround(vb[j] * rs));
        }
        __syncthreads();
        float* oS = slabS + (size_t)blockIdx.x * (NCLS * K_DIM);
        for (int i = tid; i < NCLS * K_DIM; i += 256) oS[i] = Sl[i];
        if (tid < NCLS) slabC[blockIdx.x * 64 + tid] = Cl[tid];
    }
}

// ---------------- K2: symmetric panels, 8 waves x 32 rows, LDS-staged B panel ----------------
__global__ __launch_bounds__(512) void kmain(const ushort* __restrict__ fnp,
                                             const float* __restrict__ slabS,
                                             const float* __restrict__ slabC,
                                             float* __restrict__ denomP,
                                             float* __restrict__ S,
                                             float* __restrict__ cntC) {
    __shared__ __align__(16) ushort ldsB[16 * 2048];   // 64 KB: panel J, packed layout
    __shared__ float colbuf[8][256];                   // 8 KB
    const int tid = threadIdx.x;
    const int lane = tid & 63;
    const int lrow = lane & 15;
    const int g = lane >> 4;
    const int wv = tid >> 6;           // 0..7

    // decode blockIdx.x -> (I, J), I <= J < 32; off(I) = 32I - I(I-1)/2
    const int bid = blockIdx.x;
    int I = (int)((65.0f - sqrtf(4225.0f - 8.0f * (float)bid)) * 0.5f);
    while ((I + 1) * 32 - ((I + 1) * I) / 2 <= bid) ++I;
    while (I * 32 - (I * (I - 1)) / 2 > bid) --I;
    const int J = I + (bid - (I * 32 - (I * (I - 1)) / 2));
    const bool offd = (J != I);
    const int rbase = I * 256 + wv * 32;   // this wave's 32 rows

    // ---- stage panel J (64 KB) into LDS via global_load_lds; both sides linear ----
    {
        const ushort* gbase = fnp + (size_t)J * 16 * 2048;
#pragma unroll
        for (int it = 0; it < 8; ++it) {
            const int chunk = it * 512 + wv * 64;      // wave-uniform chunk base; lane adds *16B
            const ushort* src = gbase + (size_t)(chunk + lane) * 8;
            ushort* dst = &ldsB[(size_t)chunk * 8];
            __builtin_amdgcn_global_load_lds((const __attribute__((address_space(1))) void*)src,
                                             (__attribute__((address_space(3))) void*)dst, 16, 0, 0);
        }
    }

    // persistent A fragments: rows rbase..+31, K=128 (packed, lane-linear, from global)
    s16x8 af[2][4];
#pragma unroll
    for (int m = 0; m < 2; ++m)
#pragma unroll
        for (int kk = 0; kk < 4; ++kk)
            af[m][kk] = *(const s16x8*)&fnp[(size_t)((rbase >> 4) + m) * 2048 + kk * 512 + lane * 8];

    __syncthreads();   // drains the global_load_lds queue; panel ready

    float pd[2][4] = {};  // row partials across all 4 tiles

#pragma unroll
    for (int t = 0; t < 4; ++t) {   // 4 tiles of 64 cols = panel J
        f32x4 acc[2][4] = {};
#pragma unroll
        for (int kk = 0; kk < 4; ++kk) {
            s16x8 bfr[4];
#pragma unroll
            for (int n = 0; n < 4; ++n)
                bfr[n] = *(const s16x8*)&ldsB[(size_t)(t * 4 + n) * 2048 + kk * 512 + lane * 8];
#pragma unroll
            for (int m = 0; m < 2; ++m)
#pragma unroll
                for (int n = 0; n < 4; ++n)
                    acc[m][n] = __builtin_amdgcn_mfma_f32_16x16x32_bf16(af[m][kk], bfr[n], acc[m][n], 0, 0, 0);
        }
        float pcn[4] = {0.f, 0.f, 0.f, 0.f};
#pragma unroll
        for (int m = 0; m < 2; ++m)
#pragma unroll
            for (int n = 0; n < 4; ++n)
#pragma unroll
                for (int r = 0; r < 4; ++r) {
                    const float e = fexp2(acc[m][n][r]);
                    pd[m][r] += e;
                    pcn[n] += e;
                }
        if (offd) {
#pragma unroll
            for (int n = 0; n < 4; ++n) {
                float v = pcn[n];
                v += __shfl_xor(v, 16);
                v += __shfl_xor(v, 32);
                if (lane < 16) colbuf[wv][t * 64 + n * 16 + lrow] = v;
            }
        }
    }

    // row partials -> slot J, plain store (wave owns its rows)
#pragma unroll
    for (int m = 0; m < 2; ++m)
#pragma unroll
        for (int r = 0; r < 4; ++r) {
            float v = pd[m][r];
#pragma unroll
            for (int msk = 1; msk < 16; msk <<= 1) v += __shfl_xor(v, msk, 16);
            if (lrow == 0)
                denomP[(size_t)J * M_ROWS + rbase + m * 16 + g * 4 + r] = v;
        }

    // col partials: cross-wave LDS reduce -> slot I, plain store (block-uniform branch)
    if (offd) {
        __syncthreads();
        if (tid < 256) {
            float cv = 0.f;
#pragma unroll
            for (int w = 0; w < 8; ++w) cv += colbuf[w][tid];
            denomP[(size_t)I * M_ROWS + J * 256 + tid] = cv;
        }
    }

    // tail: blocks 0-30 reduce slabs -> S, cntC (reads K1 outputs; kfin reads S next kernel)
    if (bid < 31 && tid < 256) {
        const int i = bid * 256 + tid;
        if (i < NCLS * K_DIM) {
            float s = 0.f;
#pragma unroll 8
            for (int b = 0; b < NSLAB; ++b) s += slabS[(size_t)b * (NCLS * K_DIM) + i];
            S[i] = s;
        } else if (i < NCLS * K_DIM + NCLS) {
            const int c = i - NCLS * K_DIM;
            float s = 0.f;
#pragma unroll 8
            for (int b = 0; b < NSLAB; ++b) s += slabC[b * 64 + c];
            cntC[c] = s;
        }
    }
}

// ---------------- K3: finalize: per-row loss, mean ----------------
__global__ __launch_bounds__(1024) void kfin(const ushort* __restrict__ fn,
                                             const int* __restrict__ labels,
                                             const float* __restrict__ denomP,
                                             const float* __restrict__ S,
                                             const float* __restrict__ cntC,
                                             float* __restrict__ out) {
    const int tid = threadIdx.x;
    const int wv = tid >> 6, lane = tid & 63;
    const int row = blockIdx.x * 16 + wv;
    const ushort2 qv = *(const ushort2*)&fn[(size_t)row * K_DIM + lane * 2];
    const float f0 = bf2f(qv.x), f1 = bf2f(qv.y);
    const int c = labels[row];
    const float2 sv = *(const float2*)&S[c * K_DIM + lane * 2];
    float dot = f0 * sv.x + f1 * sv.y;   // q_i . S_c  (includes self)
    float sii = f0 * f0 + f1 * f1;       // q_i . q_i
#pragma unroll
    for (int msk = 1; msk < 64; msk <<= 1) {
        dot += __shfl_xor(dot, msk, 64);
        sii += __shfl_xor(sii, msk, 64);
    }
    // gather the 32 panel-slot partials for this row
    float dsum = (lane < NPAN) ? denomP[(size_t)lane * M_ROWS + row] : 0.f;
#pragma unroll
    for (int msk = 1; msk < 32; msk <<= 1) dsum += __shfl_xor(dsum, msk, 32);

    __shared__ float ls[16];
    if (lane == 0) {
        const float cf = cntC[c];                                   // count incl. self
        const float d = fmaxf(dsum - fexp2(sii), 1e-5f);            // exclude diagonal
        const float p = (dot - sii) * LN2;                          // matched sims, excl diag
        ls[wv] = ((cf - 1.f) * __logf(d) - p) / cf;
    }
    __syncthreads();
    if (tid == 0) {
        float s = 0.f;
#pragma unroll
        for (int i = 0; i < 16; ++i) s += ls[i];
        atomicAdd(out, s * (1.0f / M_ROWS));
    }
}

extern "C" void kernel_launch(void* const* d_in, const int* in_sizes, int n_in,
                              void* d_out, int out_size, void* d_ws, size_t ws_size,
                              hipStream_t stream) {
    (void)in_sizes; (void)n_in; (void)out_size; (void)ws_size;
    const float* feat = (const float*)d_in[0];
    const int* labels = (const int*)d_in[2];   // d_in[1] (ious) unused: coef == 1
    float* out = (float*)d_out;
    char* ws = (char*)d_ws;
    ushort* fnr = (ushort*)ws;                                  // 2 MB row-major bf16
    ushort* fnp = fnr + (size_t)M_ROWS * K_DIM;                 // 2 MB packed fragment-major
    float* denomP = (float*)(fnp + (size_t)M_ROWS * K_DIM);     // 32 x 8192 x 4B = 1 MB
    float* S = denomP + (size_t)NPAN * M_ROWS;                  // 30 KB
    float* cntC = S + NCLS * K_DIM;                             // 256 B
    float* slabS = cntC + 64;                                   // 128 x 30 KB
    float* slabC = slabS + (size_t)NSLAB * NCLS * K_DIM;        // 128 x 256 B

    kprep<<<M_ROWS / 16, 256, 0, stream>>>(feat, labels, fnr, fnp, slabS, slabC, out);
    kmain<<<NSIM, 512, 0, stream>>>(fnp, slabS, slabC, denomP, S, cntC);
    kfin<<<M_ROWS / 16, 1024, 0, stream>>>(fnr, labels, denomP, S, cntC, out);
}

// Round 19
// 49.738 us; speedup vs baseline: 1.4883x; 1.1286x over previous
//
#include <hip/hip_runtime.h>
#include <hip/hip_bf16.h>

#define M_ROWS 8192
#define K_DIM 128
#define NCLS 60
#define NSLOT 64           // 2 slots per 256-col panel (h-halves / source-row halves)
#define NSIM 528           // 32*33/2 upper-triangle panel pairs
#define NSLAB 256          // class partial tables (one per kprep block)

// x = q_i . q_j where q = bf16(fhat * SCL), SCL^2 = 5*log2(e)  ->  sim = x*ln2, exp(sim) = 2^x
constexpr float SCL = 2.68579007f;     // sqrt(5 * 1.4426950408889634)
constexpr float LN2 = 0.69314718056f;

using f32x4 = __attribute__((ext_vector_type(4))) float;
using s16x8 = __attribute__((ext_vector_type(8))) short;

__device__ inline float bf2f(ushort u) {
    union { unsigned int i; float f; } v; v.i = ((unsigned int)u) << 16; return v.f;
}
__device__ inline float fexp2(float x) {
#if __has_builtin(__builtin_amdgcn_exp2f)
    return __builtin_amdgcn_exp2f(x);
#else
    return exp2f(x);
#endif
}

// packed fragment-major layout: ushort index = c16*2048 + kk*512 + lane*8
//   (c16 = row/16 block, kk = k/32, lane = g*16+lrow; one MFMA fragment per 64-lane load)

// ---------------- K1: 256 blocks x 32 rows: normalize -> fnr + fnp; class slab from LDS ----------------
__global__ __launch_bounds__(256) void kprep(const float* __restrict__ feat,
                                             const int* __restrict__ labels,
                                             ushort* __restrict__ fnr,
                                             ushort* __restrict__ fnp,
                                             float* __restrict__ slabS,
                                             float* __restrict__ slabC,
                                             float* __restrict__ out) {
    __shared__ __align__(16) ushort ln[32][128];   // 8 KB
    __shared__ float Sl[NCLS * K_DIM];             // 30 KB
    __shared__ float Cl[NCLS];
    __shared__ int lab[32];
    const int tid = threadIdx.x, wv = tid >> 6, lane = tid & 63;
    const int rbase = blockIdx.x * 32;

    for (int i = tid; i < NCLS * K_DIM; i += 256) Sl[i] = 0.f;
    if (tid < NCLS) Cl[tid] = 0.f;
    if (tid < 32) lab[tid] = labels[rbase + tid];

    // ---- part A: normalize 32 rows (8 per wave) -> fnr + ln ----
#pragma unroll
    for (int it = 0; it < 8; ++it) {
        const int r = wv * 8 + it;
        const int grow = rbase + r;
        const float2 v = *(const float2*)&feat[(size_t)grow * K_DIM + lane * 2];
        float ss = v.x * v.x + v.y * v.y;
#pragma unroll
        for (int m = 1; m < 64; m <<= 1) ss += __shfl_xor(ss, m, 64);
        const float rs = rsqrtf(ss) * SCL;
        __hip_bfloat16 ha = __float2bfloat16(v.x * rs);
        __hip_bfloat16 hb = __float2bfloat16(v.y * rs);
        ushort2 o;
        o.x = *reinterpret_cast<const ushort*>(&ha);
        o.y = *reinterpret_cast<const ushort*>(&hb);
        *(ushort2*)&fnr[(size_t)grow * K_DIM + lane * 2] = o;
        *(ushort2*)&ln[r][lane * 2] = o;
    }
    __syncthreads();

    // ---- packed fnp: 2 row-groups of 16 ----
#pragma unroll
    for (int gb = 0; gb < 2; ++gb) {
        const s16x8 vv = *(const s16x8*)&ln[gb * 16 + (tid & 15)][(tid >> 4) * 8];
        *(s16x8*)&fnp[(size_t)(blockIdx.x * 2 + gb) * 2048 + tid * 8] = vv;
    }
    if (blockIdx.x == 0 && tid == 0) out[0] = 0.f;

    // ---- part B: class partials from the LDS-resident rows (no feat re-read) ----
    const int rsub = tid >> 4;   // 16 rows concurrent
    const int kc = tid & 15;     // 16 lanes x 8 bf16 = 128 k
#pragma unroll
    for (int it = 0; it < 2; ++it) {
        const int r = it * 16 + rsub;
        const int lb = lab[r];
        if (kc == 0) atomicAdd(&Cl[lb], 1.f);
        const s16x8 q = *(const s16x8*)&ln[r][kc * 8];
        float* dst = &Sl[lb * K_DIM + kc * 8];
#pragma unroll
        for (int j = 0; j < 8; ++j) atomicAdd(&dst[j], bf2f((ushort)q[j]));
    }
    __syncthreads();
    float* oS = slabS + (size_t)blockIdx.x * (NCLS * K_DIM);
    for (int i = tid; i < NCLS * K_DIM; i += 256) oS[i] = Sl[i];
    if (tid < NCLS) slabC[blockIdx.x * 64 + tid] = Cl[tid];
}

// ---------------- K2: half-panel blocks (I,J,h), 8 waves x 32 rows, LDS-staged ----------------
// 1056 blocks = 528 pairs x 2 col-halves. Row partials -> slot 2J+h (rows of I).
// Col partials (I<J): waves 0-3 (rows I..+127) -> slot 2I; waves 4-7 -> slot 2I+1,
// at rows J*256 + h*128 + 0..127. Every (slot,row) written exactly once.
__global__ __launch_bounds__(512) void kmain(const ushort* __restrict__ fnp,
                                             const float* __restrict__ slabS,
                                             const float* __restrict__ slabC,
                                             float* __restrict__ denomP,
                                             float* __restrict__ S,
                                             float* __restrict__ cntC) {
    __shared__ __align__(16) ushort ldsB[8 * 2048];   // 32 KB: half-panel, packed layout
    __shared__ float colbuf[8][128];                  // 4 KB
    const int tid = threadIdx.x;
    const int lane = tid & 63;
    const int lrow = lane & 15;
    const int g = lane >> 4;
    const int wv = tid >> 6;           // 0..7

    const int bid = blockIdx.x;
    const int p = bid >> 1;            // pair index 0..527
    const int h = bid & 1;             // column half
    // decode p -> (I, J), I <= J < 32; off(I) = 32I - I(I-1)/2
    int I = (int)((65.0f - sqrtf(4225.0f - 8.0f * (float)p)) * 0.5f);
    while ((I + 1) * 32 - ((I + 1) * I) / 2 <= p) ++I;
    while (I * 32 - (I * (I - 1)) / 2 > p) --I;
    const int J = I + (p - (I * 32 - (I * (I - 1)) / 2));
    const bool offd = (J != I);
    const int rbase = I * 256 + wv * 32;   // this wave's 32 rows

    // ---- stage half-panel (32 KB) into LDS; both sides linear ----
    {
        const ushort* gbase = fnp + (size_t)(J * 16 + h * 8) * 2048;
#pragma unroll
        for (int it = 0; it < 4; ++it) {
            const int chunk = it * 512 + wv * 64;      // wave-uniform; lane adds *16B
            const ushort* src = gbase + (size_t)(chunk + lane) * 8;
            ushort* dst = &ldsB[(size_t)chunk * 8];
            __builtin_amdgcn_global_load_lds((const __attribute__((address_space(1))) void*)src,
                                             (__attribute__((address_space(3))) void*)dst, 16, 0, 0);
        }
    }

    // persistent A fragments: rows rbase..+31, K=128 (packed, lane-linear, from global)
    s16x8 af[2][4];
#pragma unroll
    for (int m = 0; m < 2; ++m)
#pragma unroll
        for (int kk = 0; kk < 4; ++kk)
            af[m][kk] = *(const s16x8*)&fnp[(size_t)((rbase >> 4) + m) * 2048 + kk * 512 + lane * 8];

    __syncthreads();   // drains global_load_lds; half-panel ready

    float pd[2][4] = {};  // row partials across both tiles

#pragma unroll
    for (int t = 0; t < 2; ++t) {   // 2 tiles of 64 cols
        f32x4 acc[2][4] = {};
#pragma unroll
        for (int kk = 0; kk < 4; ++kk) {
            s16x8 bfr[4];
#pragma unroll
            for (int n = 0; n < 4; ++n)
                bfr[n] = *(const s16x8*)&ldsB[(size_t)(t * 4 + n) * 2048 + kk * 512 + lane * 8];
#pragma unroll
            for (int m = 0; m < 2; ++m)
#pragma unroll
                for (int n = 0; n < 4; ++n)
                    acc[m][n] = __builtin_amdgcn_mfma_f32_16x16x32_bf16(af[m][kk], bfr[n], acc[m][n], 0, 0, 0);
        }
        float pcn[4] = {0.f, 0.f, 0.f, 0.f};
#pragma unroll
        for (int m = 0; m < 2; ++m)
#pragma unroll
            for (int n = 0; n < 4; ++n)
#pragma unroll
                for (int r = 0; r < 4; ++r) {
                    const float e = fexp2(acc[m][n][r]);
                    pd[m][r] += e;
                    pcn[n] += e;
                }
        if (offd) {
#pragma unroll
            for (int n = 0; n < 4; ++n) {
                float v = pcn[n];
                v += __shfl_xor(v, 16);
                v += __shfl_xor(v, 32);
                if (lane < 16) colbuf[wv][t * 64 + n * 16 + lrow] = v;
            }
        }
    }

    // row partials -> slot 2J+h, plain store (wave owns its rows)
#pragma unroll
    for (int m = 0; m < 2; ++m)
#pragma unroll
        for (int r = 0; r < 4; ++r) {
            float v = pd[m][r];
#pragma unroll
            for (int msk = 1; msk < 16; msk <<= 1) v += __shfl_xor(v, msk, 16);
            if (lrow == 0)
                denomP[(size_t)(2 * J + h) * M_ROWS + rbase + m * 16 + g * 4 + r] = v;
        }

    // col partials: split by source-row half -> slots 2I / 2I+1 (block-uniform branch)
    if (offd) {
        __syncthreads();
        if (tid < 128) {
            const float cv0 = colbuf[0][tid] + colbuf[1][tid] + colbuf[2][tid] + colbuf[3][tid];
            const float cv1 = colbuf[4][tid] + colbuf[5][tid] + colbuf[6][tid] + colbuf[7][tid];
            const size_t cpos = (size_t)J * 256 + h * 128 + tid;
            denomP[(size_t)(2 * I) * M_ROWS + cpos] = cv0;
            denomP[(size_t)(2 * I + 1) * M_ROWS + cpos] = cv1;
        }
    }

    // tail: blocks 0-30 reduce slabs -> S, cntC
    if (bid < 31 && tid < 256) {
        const int i = bid * 256 + tid;
        if (i < NCLS * K_DIM) {
            float s = 0.f;
#pragma unroll 8
            for (int b = 0; b < NSLAB; ++b) s += slabS[(size_t)b * (NCLS * K_DIM) + i];
            S[i] = s;
        } else if (i < NCLS * K_DIM + NCLS) {
            const int c = i - NCLS * K_DIM;
            float s = 0.f;
#pragma unroll 8
            for (int b = 0; b < NSLAB; ++b) s += slabC[b * 64 + c];
            cntC[c] = s;
        }
    }
}

// ---------------- K3: finalize: per-row loss, mean ----------------
__global__ __launch_bounds__(1024) void kfin(const ushort* __restrict__ fn,
                                             const int* __restrict__ labels,
                                             const float* __restrict__ denomP,
                                             const float* __restrict__ S,
                                             const float* __restrict__ cntC,
                                             float* __restrict__ out) {
    const int tid = threadIdx.x;
    const int wv = tid >> 6, lane = tid & 63;
    const int row = blockIdx.x * 16 + wv;
    const ushort2 qv = *(const ushort2*)&fn[(size_t)row * K_DIM + lane * 2];
    const float f0 = bf2f(qv.x), f1 = bf2f(qv.y);
    const int c = labels[row];
    const float2 sv = *(const float2*)&S[c * K_DIM + lane * 2];
    float dot = f0 * sv.x + f1 * sv.y;   // q_i . S_c  (includes self)
    float sii = f0 * f0 + f1 * f1;       // q_i . q_i
    // gather the 64 slot partials for this row (one per lane)
    float dsum = denomP[(size_t)lane * M_ROWS + row];
#pragma unroll
    for (int msk = 1; msk < 64; msk <<= 1) {
        dot += __shfl_xor(dot, msk, 64);
        sii += __shfl_xor(sii, msk, 64);
        dsum += __shfl_xor(dsum, msk, 64);
    }

    __shared__ float ls[16];
    if (lane == 0) {
        const float cf = cntC[c];                                   // count incl. self
        const float d = fmaxf(dsum - fexp2(sii), 1e-5f);            // exclude diagonal
        const float p = (dot - sii) * LN2;                          // matched sims, excl diag
        ls[wv] = ((cf - 1.f) * __logf(d) - p) / cf;
    }
    __syncthreads();
    if (tid == 0) {
        float s = 0.f;
#pragma unroll
        for (int i = 0; i < 16; ++i) s += ls[i];
        atomicAdd(out, s * (1.0f / M_ROWS));
    }
}

extern "C" void kernel_launch(void* const* d_in, const int* in_sizes, int n_in,
                              void* d_out, int out_size, void* d_ws, size_t ws_size,
                              hipStream_t stream) {
    (void)in_sizes; (void)n_in; (void)out_size; (void)ws_size;
    const float* feat = (const float*)d_in[0];
    const int* labels = (const int*)d_in[2];   // d_in[1] (ious) unused: coef == 1
    float* out = (float*)d_out;
    char* ws = (char*)d_ws;
    ushort* fnr = (ushort*)ws;                                  // 2 MB row-major bf16
    ushort* fnp = fnr + (size_t)M_ROWS * K_DIM;                 // 2 MB packed fragment-major
    float* denomP = (float*)(fnp + (size_t)M_ROWS * K_DIM);     // 64 x 8192 x 4B = 2 MB
    float* S = denomP + (size_t)NSLOT * M_ROWS;                 // 30 KB
    float* cntC = S + NCLS * K_DIM;                             // 256 B
    float* slabS = cntC + 64;                                   // 256 x 30 KB
    float* slabC = slabS + (size_t)NSLAB * NCLS * K_DIM;        // 256 x 256 B

    kprep<<<M_ROWS / 32, 256, 0, stream>>>(feat, labels, fnr, fnp, slabS, slabC, out);
    kmain<<<NSIM * 2, 512, 0, stream>>>(fnp, slabS, slabC, denomP, S, cntC);
    kfin<<<M_ROWS / 16, 1024, 0, stream>>>(fnr, labels, denomP, S, cntC, out);
}